// Round 1
// baseline (66.237 us; speedup 1.0000x reference)
//
#include <hip/hip_runtime.h>

// HashEmbedding: out[b,:] = sum_h table[hash(x[b,h]), :]
//   hash(id) = (u32(id) * 2654435761) % 1_000_000
// x: [4096, 200] int32, table: [1_000_000, 128] f32, out: [4096, 128] f32
//
// Memory-bound random gather: 819,200 rows x 512 B = 419 MB from a 512 MB
// table. One wave per batch row (lane -> float2 of the 128-dim embedding),
// indices pre-hashed into LDS so the gather loop unrolls with no dependent
// index load.

#define BUCKET        1000000u
#define EMBED_DIM     128
#define HIST          200
#define ROWS_PER_BLK  4          // 4 waves x 64 lanes = 256 threads

__global__ __launch_bounds__(256, 4)
void hashemb_kernel(const int* __restrict__ x,
                    const float* __restrict__ table,
                    float* __restrict__ out,
                    int batch) {
    __shared__ int sidx[ROWS_PER_BLK * HIST];

    const int row0 = blockIdx.x * ROWS_PER_BLK;

    // Cooperative load + hash of this block's 800 ids (coalesced, once).
    const int* xblk = x + (size_t)row0 * HIST;
    for (int i = threadIdx.x; i < ROWS_PER_BLK * HIST; i += 256) {
        unsigned int id = (unsigned int)xblk[i];
        sidx[i] = (int)((id * 2654435761u) % BUCKET);   // const mod -> magic mul
    }
    __syncthreads();

    const int wave = threadIdx.x >> 6;   // row within block
    const int lane = threadIdx.x & 63;   // lane*2 -> float2 slice of 128 dims
    const int row  = row0 + wave;
    if (row >= batch) return;

    const int* __restrict__ my = &sidx[wave * HIST];

    float accx = 0.f, accy = 0.f;
    #pragma unroll 8
    for (int h = 0; h < HIST; ++h) {
        const float2 v = *reinterpret_cast<const float2*>(
            table + (size_t)my[h] * EMBED_DIM + lane * 2);
        accx += v.x;
        accy += v.y;
    }

    float2 r;
    r.x = accx;
    r.y = accy;
    *reinterpret_cast<float2*>(out + (size_t)row * EMBED_DIM + lane * 2) = r;
}

extern "C" void kernel_launch(void* const* d_in, const int* in_sizes, int n_in,
                              void* d_out, int out_size, void* d_ws, size_t ws_size,
                              hipStream_t stream) {
    const int*   x     = (const int*)d_in[0];
    const float* table = (const float*)d_in[1];
    float*       out   = (float*)d_out;

    const int batch = in_sizes[0] / HIST;                    // 4096
    const int grid  = (batch + ROWS_PER_BLK - 1) / ROWS_PER_BLK;  // 1024

    hashemb_kernel<<<grid, 256, 0, stream>>>(x, table, out, batch);
}